// Round 6
// baseline (471.430 us; speedup 1.0000x reference)
//
#include <hip/hip_runtime.h>
#include <hip/hip_bf16.h>

// BronxLayer fused implementation for MI355X (gfx950).  Round 11 (= round 10
// resubmitted: round-10 bench died to container-infra failure, no counters;
// same signature as round 2, which cleared on identical resubmission).
// r9: 464us total; k3a 129us (prefetch worked: 156->129, occ back to 20%),
// but k3a FETCH rose 108->147MB (kml working set 4.7MB > 4MB/XCD L2,
// thrashed by round-robin block placement) and the k3b nontemporal A-load
// was wrong (A re-read by 4 nb-blocks -> +225MB HBM; "rest" grew 278->335).
// Round-10/11 changes:
//  - k3b rewrite: 384 blocks = 96 m-tiles(32) x 4 heads, full N=256 & full
//    K per block -> A read exactly ONCE (75.5MB); no K-split, no LDS.
//    Two-buffer ping-pong register prefetch (static reg names) keeps ~6KB
//    per wave in flight -> BW-bound, not latency-bound.  Plain loads.
//  - k3a: bijective XCD swizzle (2304 = 8*288): each XCD gets 6 contiguous
//    z-chunks x all x-blocks -> per-XCD kml working set 1.9MB < 4MB L2.

#define NN 3072
#define HH 256
#define NB 4
#define HD 64
constexpr int KMLSZ = 192 * 2 * 64 * 8;  // shorts per (mat,head)

typedef __attribute__((ext_vector_type(8))) short bf16x8;
typedef __attribute__((ext_vector_type(4))) float f32x4;

static __device__ inline short f2bf(float f) {
    __hip_bfloat16 h = __float2bfloat16(f);
    return __builtin_bit_cast(short, h);
}

// ---------------- k0: weight prep + zero denom/klsum ----------------
__global__ void k0_prep(const float* __restrict__ Wk, const float* __restrict__ Wmu,
                        const float* __restrict__ Wls, const float* __restrict__ bk,
                        const float* __restrict__ bmu, const float* __restrict__ bls,
                        const float* __restrict__ Wv, short* __restrict__ WTcat,
                        float* __restrict__ biascat, short* __restrict__ WvT,
                        float* __restrict__ denom) {
    __shared__ float t[64][65];
    int bx = blockIdx.x;
    if (bx < 48) {
        int mat = bx >> 4;
        int by = (bx >> 2) & 3, bc = bx & 3;
        int y0 = by * 64, c0 = bc * 64;
        const float* W = (mat == 0) ? Wk : (mat == 1 ? Wmu : Wls);
        float scale = (mat == 0) ? 0.125f : 1.f;
        int r = threadIdx.x >> 4, c4 = (threadIdx.x & 15) * 4;
#pragma unroll
        for (int i = 0; i < 4; i++) {
            int yl = r + i * 16;
            float4 v = *(const float4*)(W + (y0 + yl) * 256 + c0 + c4);
            t[yl][c4] = v.x; t[yl][c4 + 1] = v.y; t[yl][c4 + 2] = v.z; t[yl][c4 + 3] = v.w;
        }
        __syncthreads();
#pragma unroll
        for (int i = 0; i < 4; i++) {
            int cl = r + i * 16;
            int corig = c0 + cl;
            int cp = mat * 256 + (corig & 3) * 64 + (corig >> 2);
            short4 v = make_short4(f2bf(t[c4][cl] * scale), f2bf(t[c4 + 1][cl] * scale),
                                   f2bf(t[c4 + 2][cl] * scale), f2bf(t[c4 + 3][cl] * scale));
            *(short4*)(WTcat + cp * 256 + y0 + c4) = v;
        }
        return;
    }
    if (bx < 112) {
        int b = bx - 48;
        int bk2 = b >> 2, bn = b & 3;
        int k0 = bk2 * 64, n0 = bn * 64;
        int r = threadIdx.x >> 4, c4 = (threadIdx.x & 15) * 4;
#pragma unroll
        for (int i = 0; i < 4; i++) {
            int kk = r + i * 16;
            float4 v = *(const float4*)(Wv + (k0 + kk) * 256 + n0 + c4);
            t[kk][c4] = v.x; t[kk][c4 + 1] = v.y; t[kk][c4 + 2] = v.z; t[kk][c4 + 3] = v.w;
        }
        __syncthreads();
#pragma unroll
        for (int i = 0; i < 4; i++) {
            int nn = r + i * 16;
            short4 v = make_short4(f2bf(t[c4][nn]), f2bf(t[c4 + 1][nn]),
                                   f2bf(t[c4 + 2][nn]), f2bf(t[c4 + 3][nn]));
            *(short4*)(WvT + (n0 + nn) * 1024 + k0 + c4) = v;
        }
        return;
    }
    if (bx == 112) {
        int cc = threadIdx.x;
        int corig = (cc & 63) * 4 + (cc >> 6);
        biascat[cc] = bk[corig] * 0.125f;
        biascat[256 + cc] = bmu[corig];
        biascat[512 + cc] = bls[corig];
        return;
    }
    int i = (bx - 113) * 256 + threadIdx.x;
    if (i < 13312) denom[i] = 0.f;   // denom[12288] then klsum[1024], contiguous
}

// ---------------- k1: LayerNorm ----------------
__global__ void k1_ln(const float* __restrict__ h, const float* __restrict__ gamma,
                      const float* __restrict__ beta, short* __restrict__ hn) {
    int row = blockIdx.x, tid = threadIdx.x;
    float v = h[row * 256 + tid];
    float s = v, s2 = v * v;
    for (int off = 32; off; off >>= 1) {
        s += __shfl_xor(s, off);
        s2 += __shfl_xor(s2, off);
    }
    __shared__ float red[8];
    int w = tid >> 6, lane = tid & 63;
    if (!lane) { red[w] = s; red[4 + w] = s2; }
    __syncthreads();
    s = red[0] + red[1] + red[2] + red[3];
    s2 = red[4] + red[5] + red[6] + red[7];
    float mean = s * (1.f / 256.f);
    float var = s2 * (1.f / 256.f) - mean * mean;
    float rs = rsqrtf(var + 1e-5f);
    hn[row * 256 + tid] = f2bf((v - mean) * rs * gamma[tid] + beta[tid]);
}

// ---------------- k1b: transpose hn -> hnT (LDS-tiled) ----------------
__global__ void k1b_tr(const short* __restrict__ hn, short* __restrict__ hnT) {
    __shared__ short t[64][68];
    int bn = blockIdx.x >> 2, bh = blockIdx.x & 3;
    int n0 = bn * 64, h0 = bh * 64;
    int r = threadIdx.x >> 4, c4 = (threadIdx.x & 15) * 4;
#pragma unroll
    for (int i = 0; i < 4; i++) {
        int nn = r + i * 16;
        *(short4*)&t[nn][c4] = *(const short4*)(hn + (n0 + nn) * 256 + h0 + c4);
    }
    __syncthreads();
#pragma unroll
    for (int i = 0; i < 4; i++) {
        int hh = r + i * 16;
        short4 v = make_short4(t[c4][hh], t[c4 + 1][hh], t[c4 + 2][hh], t[c4 + 3][hh]);
        *(short4*)(hnT + (h0 + hh) * NN + n0 + c4) = v;
    }
}

// ---------------- k2: projections (bf16 MFMA), fragment-packed output -----------
// kml packed per (mat,head): idx = ((zt*2 + khalf)*64 + lane)*8 + j
//   element: node z = zt*16 + (lane&15), k = khalf*32 + (lane>>4)*8 + j
__global__ __launch_bounds__(256) void k2_proj(const short* __restrict__ hn,
                                               const short* __restrict__ WTcat,
                                               const float* __restrict__ biascat,
                                               short* __restrict__ kml) {
    int bx = blockIdx.x;
    int mt = bx / 12, nb = bx % 12;
    int m0 = mt * 64, n0 = nb * 64;
    int tid = threadIdx.x, w = tid >> 6, lane = tid & 63, q = lane >> 4, c = lane & 15;
    int mrow = m0 + w * 16;
    f32x4 acc[4] = {{0, 0, 0, 0}, {0, 0, 0, 0}, {0, 0, 0, 0}, {0, 0, 0, 0}};
    for (int k0 = 0; k0 < 256; k0 += 32) {
        bf16x8 af = *(const bf16x8*)(hn + (mrow + c) * 256 + k0 + q * 8);
#pragma unroll
        for (int nt = 0; nt < 4; nt++) {
            bf16x8 bf = *(const bf16x8*)(WTcat + (n0 + nt * 16 + c) * 256 + k0 + q * 8);
            acc[nt] = __builtin_amdgcn_mfma_f32_16x16x32_bf16(af, bf, acc[nt], 0, 0, 0);
        }
    }
#pragma unroll
    for (int nt = 0; nt < 4; nt++) {
        int cp = n0 + nt * 16 + c;
        float bias = biascat[cp];
        int mat = cp >> 8, b = (cp >> 6) & 3, y = cp & 63;
        short* dst = kml + (size_t)(mat * 4 + b) * KMLSZ;
        int kh2 = y >> 5, lq = (y >> 3) & 3, j = y & 7;
        int zt = mt * 4 + w;  // m>>4
#pragma unroll
        for (int r = 0; r < 4; r++) {
            int ml = 4 * q + r;  // m&15
            dst[(((zt * 2 + kh2) * 64) + lq * 16 + ml) * 8 + j] = f2bf(acc[nt][r] + bias);
        }
    }
}

// ---------------- k3a: elementwise core (barrier-free + cross-t prefetch) -------
// Block: 64 x (wave w -> x-tile xb*4+w) x 64 z.  Waves fully independent.
// XCD-swizzled block decode: each XCD gets 288 consecutive logical blocks =
// 6 contiguous z-chunks, so its kml mu/ls slice (~1.9MB) stays L2-resident.
__global__ __launch_bounds__(256) void k3a_elem(
    const short* __restrict__ kml, const float* __restrict__ eps,
    const float* __restrict__ diff, short* __restrict__ apk,
    float* __restrict__ denom, float* __restrict__ klsum) {
    __shared__ float klred[4];
    const int tid = threadIdx.x;
    const int w = tid >> 6, lane = tid & 63, q = lane >> 4, c = lane & 15;
    const int swz = (blockIdx.x & 7) * 288 + (blockIdx.x >> 3);  // bijective, 2304=8*288
    const int xb = swz % 48;
    const int zc = swz / 48;
    const int xt = xb * 4 + w;     // this wave's x-tile, 0..191
    const int x0 = xt * 16;

    // kh fragments (B-operand of S^T), hoisted: one per (head, k-half)
    bf16x8 qf[NB][2];
#pragma unroll
    for (int b = 0; b < NB; b++)
#pragma unroll
        for (int kh = 0; kh < 2; kh++)
            qf[b][kh] = *(const bf16x8*)(kml + (size_t)b * KMLSZ +
                                         ((xt * 2 + kh) * 64 + lane) * 8);

    float den_acc[NB] = {0.f, 0.f, 0.f, 0.f};
    float kl_acc = 0.f;
    const size_t xrow = (size_t)(x0 + c) * NN;

    // prologue: prefetch eps/diff for t=0
    f32x4 e_nxt[4];
    float d_nxt[4];
    {
        const int z16 = zc * 64;
#pragma unroll
        for (int r = 0; r < 4; r++) {
            e_nxt[r] = __builtin_nontemporal_load(
                (const f32x4*)(eps + (xrow + (size_t)(z16 + 4 * q + r)) * 4));
            d_nxt[r] = __builtin_nontemporal_load(diff + xrow + z16 + 4 * q + r);
        }
    }

#pragma unroll
    for (int t = 0; t < 4; t++) {
        const int zt2 = zc * 4 + t;
        // consume prefetched regs; immediately issue t+1 loads
        f32x4 e4[4];
        float dif[4];
#pragma unroll
        for (int r = 0; r < 4; r++) { e4[r] = e_nxt[r]; dif[r] = d_nxt[r]; }
        if (t < 3) {
            const int z16 = (zt2 + 1) * 16;
#pragma unroll
            for (int r = 0; r < 4; r++) {
                e_nxt[r] = __builtin_nontemporal_load(
                    (const f32x4*)(eps + (xrow + (size_t)(z16 + 4 * q + r)) * 4));
                d_nxt[r] = __builtin_nontemporal_load(diff + xrow + z16 + 4 * q + r);
            }
        }
#pragma unroll
        for (int b = 0; b < NB; b++) {
            const short* mup = kml + (size_t)(NB + b) * KMLSZ;
            const short* lsp = kml + (size_t)(2 * NB + b) * KMLSZ;
            bf16x8 a0 = *(const bf16x8*)(mup + ((zt2 * 2 + 0) * 64 + lane) * 8);
            bf16x8 a1 = *(const bf16x8*)(mup + ((zt2 * 2 + 1) * 64 + lane) * 8);
            bf16x8 l0 = *(const bf16x8*)(lsp + ((zt2 * 2 + 0) * 64 + lane) * 8);
            bf16x8 l1 = *(const bf16x8*)(lsp + ((zt2 * 2 + 1) * 64 + lane) * 8);
            f32x4 smu = {0.f, 0.f, 0.f, 0.f};
            smu = __builtin_amdgcn_mfma_f32_16x16x32_bf16(a0, qf[b][0], smu, 0, 0, 0);
            smu = __builtin_amdgcn_mfma_f32_16x16x32_bf16(a1, qf[b][1], smu, 0, 0, 0);
            f32x4 sls = {0.f, 0.f, 0.f, 0.f};
            sls = __builtin_amdgcn_mfma_f32_16x16x32_bf16(l0, qf[b][0], sls, 0, 0, 0);
            sls = __builtin_amdgcn_mfma_f32_16x16x32_bf16(l1, qf[b][1], sls, 0, 0, 0);
            short pk[4];
#pragma unroll
            for (int r = 0; r < 4; r++) {
                float mu = smu[r];
                float ls = sls[r];
                float e = e4[r][b];
                float d = dif[r];
                float ex = __expf(-fabsf(ls));
                float sg = fmaxf(ls, 0.f) + __logf(1.f + ex);
                float kle = -__logf(sg) + 0.5f * (sg * sg + mu * mu) - 0.5f;
                float sgn = (d > 0.f) ? 1.f : ((d < 0.f) ? -1.f : 0.f);
                kl_acc += sgn * kle;
                float av = __expf(mu + sg * e) * d;
                den_acc[b] += fabsf(av);
                pk[r] = f2bf(av);
            }
            // tile-packed store: wave writes 512B contiguous per (t,b)
            *(short4*)(apk + (((size_t)b * 192 + xt) * 192 + zt2) * 256 + c * 16 + q * 4) =
                make_short4(pk[0], pk[1], pk[2], pk[3]);
        }
    }
    // denominator: lane's elements all at x = x0 + c; reduce across quads
#pragma unroll
    for (int b = 0; b < NB; b++) {
        float d = den_acc[b];
        d += __shfl_down(d, 32);
        d += __shfl_down(d, 16);
        if (q == 0) atomicAdd(&denom[(x0 + c) * NB + b], d);
    }
    for (int off = 32; off; off >>= 1) kl_acc += __shfl_xor(kl_acc, off);
    if (lane == 0) klred[w] = kl_acc;
    __syncthreads();
    if (tid == 0) atomicAdd(klsum, klred[0] + klred[1] + klred[2] + klred[3]);
}

// ---------------- k3b: aggregation GEMM + normalize -> bf16 ----------------
// aggn[x, b*256+h] = (sum_z a_b[x,z] hnT[h,z]) / denom[x,b].  Grid 384 =
// 96 m-tiles(32 rows) x 4 heads; block covers full N=256 (wave w -> n-
// quarter) and full K=3072 -> A (apk) read exactly ONCE.  No K-split, no
// LDS, no barriers.  Two-buffer ping-pong register prefetch: while MFMAing
// k-step ks, loads for ks+2/ks+3 are in flight (~6KB/wave outstanding).
__global__ __launch_bounds__(256) void k3b_agg(
    const short* __restrict__ apk, const short* __restrict__ hnT,
    const float* __restrict__ denom, short* __restrict__ aggn) {
    const int tid = threadIdx.x;
    const int w = tid >> 6, lane = tid & 63, q = lane >> 4, c = lane & 15;
    const int q2 = q >> 1, q1 = q & 1;
    const int bid = blockIdx.x;
    const int b = bid & 3;
    const int mb = bid >> 2;            // 0..95
    const int m0 = mb * 32;
    const int n0 = w * 64;

    f32x4 acc[2][4];
#pragma unroll
    for (int i = 0; i < 2; i++)
#pragma unroll
        for (int j = 0; j < 4; j++) acc[i][j] = (f32x4){0.f, 0.f, 0.f, 0.f};

    // A: tile (b, xt=mb*2+mt, zt2=ks*2+q2), in-tile byte off = (c*16+q1*8)*2
    const short* abase = apk + ((size_t)b * 192 + mb * 2) * 192 * 256 + c * 16 + q1 * 8;
    // B: hnT[h][z], h = n0 + nt*16 + c, z = ks*32 + q*8
    const short* bbase = hnT + (size_t)(n0 + c) * NN + q * 8;

#define LDA(KS, MT) (*(const bf16x8*)(abase + (size_t)((MT)*192 + (KS)*2 + q2) * 256))
#define LDB(KS, NT) (*(const bf16x8*)(bbase + (size_t)(NT)*16 * NN + (KS)*32))
#define PREF(AF, BF, KS)                                       \
    do {                                                       \
        AF##0 = LDA(KS, 0); AF##1 = LDA(KS, 1);                \
        BF##0 = LDB(KS, 0); BF##1 = LDB(KS, 1);                \
        BF##2 = LDB(KS, 2); BF##3 = LDB(KS, 3);                \
    } while (0)
#define MFMA8(AF, BF)                                                           \
    do {                                                                        \
        acc[0][0] = __builtin_amdgcn_mfma_f32_16x16x32_bf16(AF##0, BF##0, acc[0][0], 0, 0, 0); \
        acc[0][1] = __builtin_amdgcn_mfma_f32_16x16x32_bf16(AF##0, BF##1, acc[0][1], 0, 0, 0); \
        acc[0][2] = __builtin_amdgcn_mfma_f32_16x16x32_bf16(AF##0, BF##2, acc[0][2], 0, 0, 0); \
        acc[0][3] = __builtin_amdgcn_mfma_f32_16x16x32_bf16(AF##0, BF##3, acc[0][3], 0, 0, 0); \
        acc[1][0] = __builtin_amdgcn_mfma_f32_16x16x32_bf16(AF##1, BF##0, acc[1][0], 0, 0, 0); \
        acc[1][1] = __builtin_amdgcn_mfma_f32_16x16x32_bf16(AF##1, BF##1, acc[1][1], 0, 0, 0); \
        acc[1][2] = __builtin_amdgcn_mfma_f32_16x16x32_bf16(AF##1, BF##2, acc[1][2], 0, 0, 0); \
        acc[1][3] = __builtin_amdgcn_mfma_f32_16x16x32_bf16(AF##1, BF##3, acc[1][3], 0, 0, 0); \
    } while (0)

    bf16x8 afA0, afA1, bfA0, bfA1, bfA2, bfA3;
    bf16x8 afB0, afB1, bfB0, bfB1, bfB2, bfB3;
    PREF(afA, bfA, 0);
    PREF(afB, bfB, 1);
    for (int ks = 0; ks < 96; ks += 2) {
        MFMA8(afA, bfA);
        if (ks + 2 < 96) PREF(afA, bfA, ks + 2);
        MFMA8(afB, bfB);
        if (ks + 3 < 96) PREF(afB, bfB, ks + 3);
    }
#undef LDA
#undef LDB
#undef PREF
#undef MFMA8

#pragma unroll
    for (int mt = 0; mt < 2; mt++)
#pragma unroll
        for (int r = 0; r < 4; r++) {
            int x = m0 + mt * 16 + 4 * q + r;
            float rcp = 1.f / fmaxf(denom[x * 4 + b], 1e-12f);
#pragma unroll
            for (int nt = 0; nt < 4; nt++)
                aggn[(size_t)x * 1024 + b * 256 + n0 + nt * 16 + c] =
                    f2bf(acc[mt][nt][r] * rcp);
        }
}

// ---------------- k4: fc_v + elu + residual + kl ----------------
__global__ __launch_bounds__(256) void k4_out(const short* __restrict__ aggn,
                                              const short* __restrict__ WvT,
                                              const float* __restrict__ bv,
                                              const float* __restrict__ h,
                                              const float* __restrict__ klsum,
                                              float* __restrict__ out) {
    int bx = blockIdx.x;
    int mt = bx >> 2, nb = bx & 3;
    int m0 = mt * 64, n0 = nb * 64;
    int tid = threadIdx.x, w = tid >> 6, lane = tid & 63, q = lane >> 4, c = lane & 15;
    int mrow = m0 + w * 16;
    f32x4 acc[4] = {{0, 0, 0, 0}, {0, 0, 0, 0}, {0, 0, 0, 0}, {0, 0, 0, 0}};
    for (int k0 = 0; k0 < 1024; k0 += 32) {
        bf16x8 af = *(const bf16x8*)(aggn + (mrow + c) * 1024 + k0 + q * 8);
#pragma unroll
        for (int nt = 0; nt < 4; nt++) {
            bf16x8 bf = *(const bf16x8*)(WvT + (n0 + nt * 16 + c) * 1024 + k0 + q * 8);
            acc[nt] = __builtin_amdgcn_mfma_f32_16x16x32_bf16(af, bf, acc[nt], 0, 0, 0);
        }
    }
#pragma unroll
    for (int nt = 0; nt < 4; nt++) {
        int col = n0 + nt * 16 + c;
        float bias = bv[col];
#pragma unroll
        for (int r = 0; r < 4; r++) {
            int row = mrow + 4 * q + r;
            float v = acc[nt][r] + bias;
            v = (v > 0.f) ? v : (__expf(v) - 1.f);  // elu
            out[row * 256 + col] = v + h[row * 256 + col];
        }
    }
    if (bx == 0 && tid == 0) out[786432] = klsum[0] * (1.0f / 9437184.0f);
}

extern "C" void kernel_launch(void* const* d_in, const int* in_sizes, int n_in,
                              void* d_out, int out_size, void* d_ws, size_t ws_size,
                              hipStream_t stream) {
    const float* h = (const float*)d_in[0];
    const float* gamma = (const float*)d_in[1];
    const float* beta = (const float*)d_in[2];
    const float* Wk = (const float*)d_in[3];
    const float* bk = (const float*)d_in[4];
    const float* Wmu = (const float*)d_in[5];
    const float* bmu = (const float*)d_in[6];
    const float* Wls = (const float*)d_in[7];
    const float* bls = (const float*)d_in[8];
    const float* Wv = (const float*)d_in[9];
    const float* bv = (const float*)d_in[10];
    const float* diff = (const float*)d_in[11];
    const float* eps = (const float*)d_in[12];
    float* out = (float*)d_out;

    char* p = (char*)d_ws;
    short* apk = (short*)p;    p += (size_t)75497472;  // a tile-packed, 75.5 MB
    float* denom = (float*)p;  p += 49152;             // + klsum contiguous
    float* klsum = (float*)p;  p += 4096;
    short* hn = (short*)p;     p += 1572864;
    short* hnT = (short*)p;    p += 1572864;
    short* kml = (short*)p;    p += 4718592;           // fragment-packed
    short* WTcat = (short*)p;  p += 393216;
    float* biasc = (float*)p;  p += 4096;
    short* WvT = (short*)p;    p += 524288;
    short* aggn = (short*)p;                           // 6291456; total ~90.6 MB

    k0_prep<<<165, 256, 0, stream>>>(Wk, Wmu, Wls, bk, bmu, bls, Wv, WTcat, biasc, WvT,
                                     denom);
    k1_ln<<<3072, 256, 0, stream>>>(h, gamma, beta, hn);
    k1b_tr<<<192, 256, 0, stream>>>(hn, hnT);
    k2_proj<<<576, 256, 0, stream>>>(hn, WTcat, biasc, kml);
    k3a_elem<<<48 * 48, 256, 0, stream>>>(kml, eps, diff, apk, denom, klsum);
    k3b_agg<<<384, 256, 0, stream>>>(apk, hnT, denom, aggn);
    k4_out<<<192, 256, 0, stream>>>(aggn, WvT, bv, h, klsum, out);
}